// Round 17
// baseline (542.706 us; speedup 1.0000x reference)
//
#include <hip/hip_runtime.h>
#include <hip/hip_bf16.h>

#define N_NODES 50000
#define N_EDGES 800000
#define M_PAD   50048   // 391 * 128
#define SCAN_B  512

typedef short short8 __attribute__((ext_vector_type(8)));
typedef float f32x4  __attribute__((ext_vector_type(4)));
typedef float f32x2  __attribute__((ext_vector_type(2)));
typedef unsigned short u16;
typedef unsigned char  u8;

#if __has_builtin(__builtin_amdgcn_cvt_pk_f32_fp8) && __has_builtin(__builtin_amdgcn_cvt_pk_fp8_f32)
#define HW_FP8 1
#endif

__device__ __forceinline__ float b2f(unsigned bits16) {
  return __uint_as_float(bits16 << 16);
}
__device__ __forceinline__ u16 f2b(float f) {   // RNE f32 -> bf16
  unsigned u = __float_as_uint(f);
  unsigned r = (u + 0x7fffu + ((u >> 16) & 1u)) >> 16;
  return (u16)r;
}
// software f32 -> fp8 e4m3 (RNE, flush |v|<2^-6 to 0; OCP-compatible bytes)
__device__ __forceinline__ unsigned f2q_sw(float f) {
  unsigned u = __float_as_uint(f);
  unsigned s = (u >> 24) & 0x80u;
  unsigned mag = u & 0x7fffffffu;
  mag += 0x7ffffu + ((mag >> 20) & 1u);
  int e = (int)(mag >> 23) - 120;
  if (e <= 0) return s;
  if (e > 15) e = 15;
  return s | ((unsigned)e << 3) | ((mag >> 20) & 7u);
}
// software fp8 e4m3 -> f32 (sw encoder never emits denormals)
__device__ __forceinline__ float q2f_sw(unsigned q) {
  unsigned s = (q & 0x80u) << 24;
  unsigned em = q & 0x7fu;
  if (em == 0) return __uint_as_float(s);
  return __uint_as_float(s | ((em + 960u) << 20));
}

// pack 4 floats -> 4 fp8 bytes
__device__ __forceinline__ unsigned pack_q4(float a, float b, float c, float d) {
#ifdef HW_FP8
  int w = __builtin_amdgcn_cvt_pk_fp8_f32(a, b, 0, false);
  w = __builtin_amdgcn_cvt_pk_fp8_f32(c, d, w, true);
  return (unsigned)w;
#else
  return f2q_sw(a) | (f2q_sw(b) << 8) | (f2q_sw(c) << 16) | (f2q_sw(d) << 24);
#endif
}

// ---------------- CSR build ----------------
__global__ void k_zero2(int* __restrict__ a, int* __restrict__ b, int n) {
  int i = blockIdx.x * blockDim.x + threadIdx.x;
  if (i < n) { a[i] = 0; b[i] = 0; }
}

__global__ void k_count(const int* __restrict__ dst, int* __restrict__ cnt) {
  int e = blockIdx.x * blockDim.x + threadIdx.x;
  if (e < N_EDGES) atomicAdd(&cnt[dst[e]], 1);
}

__global__ void k_scan1(const int* __restrict__ c, int* __restrict__ partial,
                        int* __restrict__ bsum, int n) {
  __shared__ int s[SCAN_B];
  int i = blockIdx.x * SCAN_B + threadIdx.x;
  int v = (i < n) ? c[i] : 0;
  s[threadIdx.x] = v;
  __syncthreads();
  for (int off = 1; off < SCAN_B; off <<= 1) {
    int t = (threadIdx.x >= off) ? s[threadIdx.x - off] : 0;
    __syncthreads();
    s[threadIdx.x] += t;
    __syncthreads();
  }
  if (i < n) partial[i] = s[threadIdx.x];
  if (threadIdx.x == SCAN_B - 1) bsum[blockIdx.x] = s[SCAN_B - 1];
}

__global__ void k_scan2(int* __restrict__ bsum, int nb) {
  if (threadIdx.x == 0 && blockIdx.x == 0) {
    int acc = 0;
    for (int b = 0; b < nb; ++b) { int t = bsum[b]; bsum[b] = acc; acc += t; }
  }
}

__global__ void k_scan3(const int* __restrict__ partial, const int* __restrict__ bsum,
                        int* __restrict__ row_ptr, float* __restrict__ inv_deg,
                        const int* __restrict__ cnt, int n) {
  int i = blockIdx.x * blockDim.x + threadIdx.x;
  if (i == 0) row_ptr[0] = 0;
  if (i < n) {
    row_ptr[i + 1] = partial[i] + bsum[i / SCAN_B];
    int d = cnt[i];
    inv_deg[i] = 1.0f / (float)(d > 1 ? d : 1);
  }
}

__global__ void k_fill(const int* __restrict__ src, const int* __restrict__ dst,
                       const int* __restrict__ row_ptr, int* __restrict__ fillc,
                       int* __restrict__ col) {
  int e = blockIdx.x * blockDim.x + threadIdx.x;
  if (e < N_EDGES) {
    int d = dst[e];
    int pos = row_ptr[d] + atomicAdd(&fillc[d], 1);
    col[pos] = src[e];
  }
}

// ---------------- conversions ----------------
// fused: x fp32 -> bf16 (pad rows zeroed) + fp8 (single read of x)
__global__ void k_cvt_xq(const float* __restrict__ in, u16* __restrict__ outb,
                         u8* __restrict__ outq) {
  int i = blockIdx.x * blockDim.x + threadIdx.x;
  const int total = M_PAD * 512 / 4;
  if (i >= total) return;
  float4 v = make_float4(0.f, 0.f, 0.f, 0.f);
  if (i < N_NODES * 512 / 4) v = ((const float4*)in)[i];
  unsigned lo = (unsigned)f2b(v.x) | ((unsigned)f2b(v.y) << 16);
  unsigned hi = (unsigned)f2b(v.z) | ((unsigned)f2b(v.w) << 16);
  ((uint2*)outb)[i] = make_uint2(lo, hi);
  ((unsigned*)outq)[i] = pack_q4(v.x, v.y, v.z, v.w);
}

// one kernel converting all six weight matrices (bf16), W3 concatenated [W3_r; W3_l]
__global__ void k_cvt_w(const float* __restrict__ w1l, const float* __restrict__ w1r,
                        const float* __restrict__ w2l, const float* __restrict__ w2r,
                        const float* __restrict__ w3r, const float* __restrict__ w3l,
                        u16* __restrict__ W1lb, u16* __restrict__ W1rb,
                        u16* __restrict__ W2lb, u16* __restrict__ W2rb,
                        u16* __restrict__ W3cat) {
  int i = blockIdx.x * blockDim.x + threadIdx.x;   // float4 index, total 327680
  const int S = 65536;   // 512*512/4
  const int S3 = 32768;  // 256*512/4
  const float* src; u16* dst; int o;
  if      (i <  S)          { src = w1l; dst = W1lb;            o = i; }
  else if (i <  2 * S)      { src = w1r; dst = W1rb;            o = i - S; }
  else if (i <  3 * S)      { src = w2l; dst = W2lb;            o = i - 2 * S; }
  else if (i <  4 * S)      { src = w2r; dst = W2rb;            o = i - 3 * S; }
  else if (i <  4 * S + S3) { src = w3r; dst = W3cat;           o = i - 4 * S; }
  else if (i <  4 * S + 2 * S3) { src = w3l; dst = W3cat + 256 * 512; o = i - 4 * S - S3; }
  else return;
  float4 v = ((const float4*)src)[o];
  unsigned lo = (unsigned)f2b(v.x) | ((unsigned)f2b(v.y) << 16);
  unsigned hi = (unsigned)f2b(v.z) | ((unsigned)f2b(v.w) << 16);
  ((uint2*)dst)[o] = make_uint2(lo, hi);
}

// ---------------- mean aggregation, d=512 (fp8 in, fp32 accum, bf16 out) ----------------
#ifdef HW_FP8
#define ACCQ(v)                                                               \
  do {                                                                        \
    acc2[0] += __builtin_amdgcn_cvt_pk_f32_fp8((int)(v).x, false);            \
    acc2[1] += __builtin_amdgcn_cvt_pk_f32_fp8((int)(v).x, true);             \
    acc2[2] += __builtin_amdgcn_cvt_pk_f32_fp8((int)(v).y, false);            \
    acc2[3] += __builtin_amdgcn_cvt_pk_f32_fp8((int)(v).y, true);             \
  } while (0)
#else
#define ACCQ(v)                                                               \
  do {                                                                        \
    acc2[0][0] += q2f_sw((v).x & 0xffu);         acc2[0][1] += q2f_sw(((v).x >> 8) & 0xffu);  \
    acc2[1][0] += q2f_sw(((v).x >> 16) & 0xffu); acc2[1][1] += q2f_sw((v).x >> 24);           \
    acc2[2][0] += q2f_sw((v).y & 0xffu);         acc2[2][1] += q2f_sw(((v).y >> 8) & 0xffu);  \
    acc2[3][0] += q2f_sw(((v).y >> 16) & 0xffu); acc2[3][1] += q2f_sw((v).y >> 24);           \
  } while (0)
#endif

__global__ __launch_bounds__(64) void k_agg8(
    const u8* __restrict__ xq, const int* __restrict__ row_ptr,
    const int* __restrict__ col, const float* __restrict__ inv_deg,
    u16* __restrict__ agg) {
  int node = blockIdx.x;
  int lane = threadIdx.x;
  int beg = row_ptr[node], end = row_ptr[node + 1];
  f32x2 acc2[4];
  #pragma unroll
  for (int i = 0; i < 4; ++i) acc2[i] = (f32x2){0.f, 0.f};
  int e = beg;
  for (; e + 4 <= end; e += 4) {
    int s0 = col[e], s1 = col[e + 1], s2 = col[e + 2], s3 = col[e + 3];
    uint2 v0 = *(const uint2*)&xq[(size_t)s0 * 512 + lane * 8];
    uint2 v1 = *(const uint2*)&xq[(size_t)s1 * 512 + lane * 8];
    uint2 v2 = *(const uint2*)&xq[(size_t)s2 * 512 + lane * 8];
    uint2 v3 = *(const uint2*)&xq[(size_t)s3 * 512 + lane * 8];
    ACCQ(v0); ACCQ(v1); ACCQ(v2); ACCQ(v3);
  }
  for (; e < end; ++e) {
    int s = col[e];
    uint2 v = *(const uint2*)&xq[(size_t)s * 512 + lane * 8];
    ACCQ(v);
  }
  float inv = inv_deg[node];
  uint4 ov;
  ov.x = (unsigned)f2b(acc2[0][0] * inv) | ((unsigned)f2b(acc2[0][1] * inv) << 16);
  ov.y = (unsigned)f2b(acc2[1][0] * inv) | ((unsigned)f2b(acc2[1][1] * inv) << 16);
  ov.z = (unsigned)f2b(acc2[2][0] * inv) | ((unsigned)f2b(acc2[2][1] * inv) << 16);
  ov.w = (unsigned)f2b(acc2[3][0] * inv) | ((unsigned)f2b(acc2[3][1] * inv) << 16);
  *(uint4*)&agg[(size_t)node * 512 + lane * 8] = ov;
}

// ---------------- layer-3 finish: out = r + mean_j t[j]  (write-only out) ----------------
#define ACC4(v)                                                     \
  do {                                                              \
    acc[0] += b2f((v).x & 0xffffu); acc[1] += b2f((v).x >> 16);     \
    acc[2] += b2f((v).y & 0xffffu); acc[3] += b2f((v).y >> 16);     \
  } while (0)

__global__ __launch_bounds__(64) void k_agg_add(
    const u16* __restrict__ t, const u16* __restrict__ r,
    const int* __restrict__ row_ptr,
    const int* __restrict__ col, const float* __restrict__ inv_deg,
    float* __restrict__ out) {
  int node = blockIdx.x;
  int lane = threadIdx.x;
  int beg = row_ptr[node], end = row_ptr[node + 1];
  float acc[4] = {0.f, 0.f, 0.f, 0.f};
  int e = beg;
  for (; e + 4 <= end; e += 4) {
    int s0 = col[e], s1 = col[e + 1], s2 = col[e + 2], s3 = col[e + 3];
    uint2 v0 = *(const uint2*)&t[(size_t)s0 * 256 + lane * 4];
    uint2 v1 = *(const uint2*)&t[(size_t)s1 * 256 + lane * 4];
    uint2 v2 = *(const uint2*)&t[(size_t)s2 * 256 + lane * 4];
    uint2 v3 = *(const uint2*)&t[(size_t)s3 * 256 + lane * 4];
    ACC4(v0); ACC4(v1); ACC4(v2); ACC4(v3);
  }
  for (; e < end; ++e) {
    int s = col[e];
    uint2 v = *(const uint2*)&t[(size_t)s * 256 + lane * 4];
    ACC4(v);
  }
  float inv = inv_deg[node];
  uint2 rv = *(const uint2*)&r[(size_t)node * 256 + lane * 4];
  float4 o;
  o.x = b2f(rv.x & 0xffffu) + acc[0] * inv;
  o.y = b2f(rv.x >> 16)     + acc[1] * inv;
  o.z = b2f(rv.y & 0xffffu) + acc[2] * inv;
  o.w = b2f(rv.y >> 16)     + acc[3] * inv;
  *(float4*)&out[(size_t)node * 256 + lane * 4] = o;
}

// ---------------- bf16 MFMA GEMM, XCD swizzle + LDS-coalesced bf16 epilogue ----------------
// C = sum_p A_p@W_p^T (+ bias) (, relu).  W row-major [O][K], K=512.
// mode 0: bf16 Cout (+ optional fp8 Cq), all rows  [LDS-coalesced stores]
// mode 2: cols<256 -> bf16 (Cout, pitch 256, +bias); cols>=256 -> bf16 tout (pitch 256)
#define BM 128
#define BN 128
#define BK 64
#define CT_LD 136   // C-tile LDS row pitch in u16

__global__ __launch_bounds__(256, 4) void k_gemm_mfma(
    const u16* __restrict__ A1, const u16* __restrict__ W1,
    const u16* __restrict__ A2, const u16* __restrict__ W2,
    const float* __restrict__ bias, void* __restrict__ Cout,
    u8* __restrict__ Cq, u16* __restrict__ tout,
    int O, int relu, int mode, int npass, int NX) {
  __shared__ __align__(16) u16 smem[17408];   // sA[0:8192) sB[8192:16384); ctile 128xCT_LD
  const int K = 512;
  int tid = threadIdx.x;
  int wave = tid >> 6, lane = tid & 63;

  // bijective XCD swizzle (m204)
  int nwg = gridDim.x;
  int q = nwg >> 3, r = nwg & 7;
  int xcd = blockIdx.x & 7, lin = blockIdx.x >> 3;
  int wgid = (xcd < r) ? (xcd * (q + 1) + lin)
                       : (r * (q + 1) + (xcd - r) * q + lin);
  int bx = wgid % NX, by = wgid / NX;
  int row0 = by * BM;
  int col0 = bx * BN;

  f32x4 acc[4][4];
  #pragma unroll
  for (int m = 0; m < 4; ++m)
    #pragma unroll
    for (int n = 0; n < 4; ++n)
      acc[m][n] = (f32x4){0.f, 0.f, 0.f, 0.f};

  int lrow = lane >> 3;
  int lk   = (lane & 7) * 8;
  int wr = (wave >> 1) * 64, wc = (wave & 1) * 64;
  int fr = lane & 15, fg = lane >> 4;

  for (int pass = 0; pass < npass; ++pass) {
    const u16* __restrict__ A = pass ? A2 : A1;
    const u16* __restrict__ W = pass ? W2 : W1;
    for (int k0 = 0; k0 < K; k0 += BK) {
      __syncthreads();
      #pragma unroll
      for (int i = 0; i < 4; ++i) {
        int chunk = i * 4 + wave;
        const u16* g = A + (size_t)(row0 + chunk * 8 + lrow) * K + k0 + lk;
        __builtin_amdgcn_global_load_lds(
            (const __attribute__((address_space(1))) void*)g,
            (__attribute__((address_space(3))) void*)&smem[chunk * 512],
            16, 0, 0);
      }
      #pragma unroll
      for (int i = 0; i < 4; ++i) {
        int chunk = i * 4 + wave;
        const u16* g = W + (size_t)(col0 + chunk * 8 + lrow) * K + k0 + lk;
        __builtin_amdgcn_global_load_lds(
            (const __attribute__((address_space(1))) void*)g,
            (__attribute__((address_space(3))) void*)&smem[8192 + chunk * 512],
            16, 0, 0);
      }
      __syncthreads();

      #pragma unroll
      for (int ks = 0; ks < 2; ++ks) {
        short8 a[4], b[4];
        #pragma unroll
        for (int m = 0; m < 4; ++m)
          a[m] = *(const short8*)&smem[(wr + m * 16 + fr) * BK + ks * 32 + fg * 8];
        #pragma unroll
        for (int n = 0; n < 4; ++n)
          b[n] = *(const short8*)&smem[8192 + (wc + n * 16 + fr) * BK + ks * 32 + fg * 8];
        #pragma unroll
        for (int m = 0; m < 4; ++m)
          #pragma unroll
          for (int n = 0; n < 4; ++n)
            acc[m][n] = __builtin_amdgcn_mfma_f32_16x16x32_bf16(
                a[m], b[n], acc[m][n], 0, 0, 0);
      }
    }
  }

  // all-bf16 LDS-coalesced epilogue (modes 0 and 2)
  __syncthreads();
  #pragma unroll
  for (int n = 0; n < 4; ++n) {
    int lc = wc + n * 16 + fr;
    float bv = 0.f;
    if (mode == 0) bv = bias[col0 + lc];
    else if (col0 < 256) bv = bias[col0 + lc];   // mode 2, r-half carries b3
    #pragma unroll
    for (int m = 0; m < 4; ++m) {
      #pragma unroll
      for (int j = 0; j < 4; ++j) {
        float v = acc[m][n][j] + bv;
        if (relu) v = fmaxf(v, 0.f);
        smem[(wr + m * 16 + fg * 4 + j) * CT_LD + lc] = f2b(v);
      }
    }
  }
  __syncthreads();
  #pragma unroll
  for (int it = 0; it < 8; ++it) {
    int idx = it * 256 + tid;       // 0..2047 covers 128 rows x 16 col-chunks
    int rr = idx >> 4, cc = (idx & 15) * 8;
    uint4 v = *(uint4*)&smem[rr * CT_LD + cc];
    int gr = row0 + rr;
    if (mode == 0) {
      int gc = col0 + cc;
      *(uint4*)&((u16*)Cout)[(size_t)gr * O + gc] = v;
      if (Cq) {
        unsigned w0 = pack_q4(b2f(v.x & 0xffffu), b2f(v.x >> 16),
                              b2f(v.y & 0xffffu), b2f(v.y >> 16));
        unsigned w1 = pack_q4(b2f(v.z & 0xffffu), b2f(v.z >> 16),
                              b2f(v.w & 0xffffu), b2f(v.w >> 16));
        *(uint2*)&Cq[(size_t)gr * O + gc] = make_uint2(w0, w1);
      }
    } else {   // mode 2
      if (col0 < 256) {
        *(uint4*)&((u16*)Cout)[(size_t)gr * 256 + col0 + cc] = v;      // r (bf16)
      } else {
        *(uint4*)&tout[(size_t)gr * 256 + (col0 - 256) + cc] = v;      // t (bf16)
      }
    }
  }
}

extern "C" void kernel_launch(void* const* d_in, const int* in_sizes, int n_in,
                              void* d_out, int out_size, void* d_ws, size_t ws_size,
                              hipStream_t stream) {
  const float* x    = (const float*)d_in[0];
  const int*   edge = (const int*)d_in[1];
  const int*   srcp = edge;
  const int*   dstp = edge + N_EDGES;
  const float* W1_l = (const float*)d_in[2];
  const float* b1   = (const float*)d_in[3];
  const float* W1_r = (const float*)d_in[4];
  const float* W2_l = (const float*)d_in[5];
  const float* b2   = (const float*)d_in[6];
  const float* W2_r = (const float*)d_in[7];
  const float* W3_l = (const float*)d_in[8];
  const float* b3   = (const float*)d_in[9];
  const float* W3_r = (const float*)d_in[10];
  float* out = (float*)d_out;

  char* ws = (char*)d_ws;
  size_t off = 0;
  auto alloc = [&](size_t bytes) -> void* {
    void* p = ws + off;
    off = (off + bytes + 255) & ~(size_t)255;
    return p;
  };
  u16* xb    = (u16*)alloc((size_t)M_PAD * 512 * 2);
  u16* aggb  = (u16*)alloc((size_t)M_PAD * 512 * 2);   // also reused as t (M_PAD x 256)
  u16* h1b   = (u16*)alloc((size_t)M_PAD * 512 * 2);   // also reused as r (M_PAD x 256) in layer 3
  u16* h2b   = (u16*)alloc((size_t)M_PAD * 512 * 2);
  u8*  qbuf  = (u8*)alloc((size_t)M_PAD * 512);        // xq for layer1, then h1q for layer2
  u16* W1lb  = (u16*)alloc((size_t)512 * 512 * 2);
  u16* W1rb  = (u16*)alloc((size_t)512 * 512 * 2);
  u16* W2lb  = (u16*)alloc((size_t)512 * 512 * 2);
  u16* W2rb  = (u16*)alloc((size_t)512 * 512 * 2);
  u16* W3cat = (u16*)alloc((size_t)512 * 512 * 2);     // rows 0-255 = W3_r, 256-511 = W3_l
  int*   cnt     = (int*)alloc((size_t)N_NODES * 4);
  int*   partial = (int*)alloc((size_t)N_NODES * 4);
  int*   bsum    = (int*)alloc(512 * 4);
  int*   row_ptr = (int*)alloc((size_t)(N_NODES + 1) * 4);
  int*   fillc   = (int*)alloc((size_t)N_NODES * 4);
  int*   col     = (int*)alloc((size_t)N_EDGES * 4);
  float* inv_deg = (float*)alloc((size_t)N_NODES * 4);
  (void)ws_size; (void)in_sizes; (void)n_in; (void)out_size;

  // ---- CSR build ----
  k_zero2<<<(N_NODES + 255) / 256, 256, 0, stream>>>(cnt, fillc, N_NODES);
  k_count<<<(N_EDGES + 255) / 256, 256, 0, stream>>>(dstp, cnt);
  int nb = (N_NODES + SCAN_B - 1) / SCAN_B;
  k_scan1<<<nb, SCAN_B, 0, stream>>>(cnt, partial, bsum, N_NODES);
  k_scan2<<<1, 64, 0, stream>>>(bsum, nb);
  k_scan3<<<(N_NODES + 255) / 256, 256, 0, stream>>>(partial, bsum, row_ptr, inv_deg, cnt, N_NODES);
  k_fill<<<(N_EDGES + 255) / 256, 256, 0, stream>>>(srcp, dstp, row_ptr, fillc, col);

  // ---- dtype conversions (2 launches) ----
  {
    int tx = M_PAD * 512 / 4;
    k_cvt_xq<<<(tx + 255) / 256, 256, 0, stream>>>(x, xb, qbuf);
    int tw = 4 * 65536 + 2 * 32768;   // 327680 float4s
    k_cvt_w<<<(tw + 255) / 256, 256, 0, stream>>>(W1_l, W1_r, W2_l, W2_r, W3_r, W3_l,
                                                  W1lb, W1rb, W2lb, W2rb, W3cat);
  }

  const int NWG = 4 * (M_PAD / BM);   // 1564 blocks, NX=4 (O=512)

  // ---- layer 1 ----  (agg reads xq fp8; gemm writes h1 bf16 + h1q fp8 into qbuf)
  k_agg8<<<N_NODES, 64, 0, stream>>>(qbuf, row_ptr, col, inv_deg, aggb);
  k_gemm_mfma<<<NWG, 256, 0, stream>>>(aggb, W1lb, xb, W1rb, b1, h1b, qbuf, nullptr,
                                       512, 1, 0, 2, 4);
  // ---- layer 2 ----  (agg reads h1q fp8)
  k_agg8<<<N_NODES, 64, 0, stream>>>(qbuf, row_ptr, col, inv_deg, aggb);
  k_gemm_mfma<<<NWG, 256, 0, stream>>>(aggb, W2lb, h1b, W2rb, b2, h2b, nullptr, nullptr,
                                       512, 1, 0, 2, 4);
  // ---- layer 3: single GEMM over [W3_r; W3_l]; r -> h1b (bf16,+b3), t -> aggb (bf16) ----
  k_gemm_mfma<<<NWG, 256, 0, stream>>>(h2b, W3cat, nullptr, nullptr, b3, h1b, nullptr, aggb,
                                       512, 0, 2, 1, 4);
  // out = r + mean-aggregate(t)   (write-only out)
  k_agg_add<<<N_NODES, 64, 0, stream>>>(aggb, h1b, row_ptr, col, inv_deg, out);
}

// Round 18
// 517.078 us; speedup vs baseline: 1.0496x; 1.0496x over previous
//
#include <hip/hip_runtime.h>
#include <hip/hip_bf16.h>

#define N_NODES 50000
#define N_EDGES 800000
#define M_PAD   50048   // 391 * 128
#define SCAN_B  512

typedef short short8 __attribute__((ext_vector_type(8)));
typedef float f32x4  __attribute__((ext_vector_type(4)));
typedef float f32x2  __attribute__((ext_vector_type(2)));
typedef unsigned short u16;
typedef unsigned char  u8;

#if __has_builtin(__builtin_amdgcn_cvt_pk_f32_fp8) && __has_builtin(__builtin_amdgcn_cvt_pk_fp8_f32)
#define HW_FP8 1
#endif

__device__ __forceinline__ float b2f(unsigned bits16) {
  return __uint_as_float(bits16 << 16);
}
__device__ __forceinline__ u16 f2b(float f) {   // RNE f32 -> bf16
  unsigned u = __float_as_uint(f);
  unsigned r = (u + 0x7fffu + ((u >> 16) & 1u)) >> 16;
  return (u16)r;
}
// software f32 -> fp8 e4m3 (RNE, flush |v|<2^-6 to 0; OCP-compatible bytes)
__device__ __forceinline__ unsigned f2q_sw(float f) {
  unsigned u = __float_as_uint(f);
  unsigned s = (u >> 24) & 0x80u;
  unsigned mag = u & 0x7fffffffu;
  mag += 0x7ffffu + ((mag >> 20) & 1u);
  int e = (int)(mag >> 23) - 120;
  if (e <= 0) return s;
  if (e > 15) e = 15;
  return s | ((unsigned)e << 3) | ((mag >> 20) & 7u);
}
// software fp8 e4m3 -> f32 (sw encoder never emits denormals)
__device__ __forceinline__ float q2f_sw(unsigned q) {
  unsigned s = (q & 0x80u) << 24;
  unsigned em = q & 0x7fu;
  if (em == 0) return __uint_as_float(s);
  return __uint_as_float(s | ((em + 960u) << 20));
}

// pack 4 floats -> 4 fp8 bytes
__device__ __forceinline__ unsigned pack_q4(float a, float b, float c, float d) {
#ifdef HW_FP8
  int w = __builtin_amdgcn_cvt_pk_fp8_f32(a, b, 0, false);
  w = __builtin_amdgcn_cvt_pk_fp8_f32(c, d, w, true);
  return (unsigned)w;
#else
  return f2q_sw(a) | (f2q_sw(b) << 8) | (f2q_sw(c) << 16) | (f2q_sw(d) << 24);
#endif
}

// ---------------- CSR build ----------------
__global__ void k_zero2(int* __restrict__ a, int* __restrict__ b, int n) {
  int i = blockIdx.x * blockDim.x + threadIdx.x;
  if (i < n) { a[i] = 0; b[i] = 0; }
}

__global__ void k_count(const int* __restrict__ dst, int* __restrict__ cnt) {
  int e = blockIdx.x * blockDim.x + threadIdx.x;
  if (e < N_EDGES) atomicAdd(&cnt[dst[e]], 1);
}

__global__ void k_scan1(const int* __restrict__ c, int* __restrict__ partial,
                        int* __restrict__ bsum, int n) {
  __shared__ int s[SCAN_B];
  int i = blockIdx.x * SCAN_B + threadIdx.x;
  int v = (i < n) ? c[i] : 0;
  s[threadIdx.x] = v;
  __syncthreads();
  for (int off = 1; off < SCAN_B; off <<= 1) {
    int t = (threadIdx.x >= off) ? s[threadIdx.x - off] : 0;
    __syncthreads();
    s[threadIdx.x] += t;
    __syncthreads();
  }
  if (i < n) partial[i] = s[threadIdx.x];
  if (threadIdx.x == SCAN_B - 1) bsum[blockIdx.x] = s[SCAN_B - 1];
}

__global__ void k_scan2(int* __restrict__ bsum, int nb) {
  if (threadIdx.x == 0 && blockIdx.x == 0) {
    int acc = 0;
    for (int b = 0; b < nb; ++b) { int t = bsum[b]; bsum[b] = acc; acc += t; }
  }
}

__global__ void k_scan3(const int* __restrict__ partial, const int* __restrict__ bsum,
                        int* __restrict__ row_ptr, float* __restrict__ inv_deg,
                        const int* __restrict__ cnt, int n) {
  int i = blockIdx.x * blockDim.x + threadIdx.x;
  if (i == 0) row_ptr[0] = 0;
  if (i < n) {
    row_ptr[i + 1] = partial[i] + bsum[i / SCAN_B];
    int d = cnt[i];
    inv_deg[i] = 1.0f / (float)(d > 1 ? d : 1);
  }
}

__global__ void k_fill(const int* __restrict__ src, const int* __restrict__ dst,
                       const int* __restrict__ row_ptr, int* __restrict__ fillc,
                       int* __restrict__ col) {
  int e = blockIdx.x * blockDim.x + threadIdx.x;
  if (e < N_EDGES) {
    int d = dst[e];
    int pos = row_ptr[d] + atomicAdd(&fillc[d], 1);
    col[pos] = src[e];
  }
}

// ---------------- conversions ----------------
// fused: x fp32 -> bf16 (pad rows zeroed) + fp8 (single read of x)
__global__ void k_cvt_xq(const float* __restrict__ in, u16* __restrict__ outb,
                         u8* __restrict__ outq) {
  int i = blockIdx.x * blockDim.x + threadIdx.x;
  const int total = M_PAD * 512 / 4;
  if (i >= total) return;
  float4 v = make_float4(0.f, 0.f, 0.f, 0.f);
  if (i < N_NODES * 512 / 4) v = ((const float4*)in)[i];
  unsigned lo = (unsigned)f2b(v.x) | ((unsigned)f2b(v.y) << 16);
  unsigned hi = (unsigned)f2b(v.z) | ((unsigned)f2b(v.w) << 16);
  ((uint2*)outb)[i] = make_uint2(lo, hi);
  ((unsigned*)outq)[i] = pack_q4(v.x, v.y, v.z, v.w);
}

// one kernel converting all six weight matrices (bf16), W3 concatenated [W3_r; W3_l]
__global__ void k_cvt_w(const float* __restrict__ w1l, const float* __restrict__ w1r,
                        const float* __restrict__ w2l, const float* __restrict__ w2r,
                        const float* __restrict__ w3r, const float* __restrict__ w3l,
                        u16* __restrict__ W1lb, u16* __restrict__ W1rb,
                        u16* __restrict__ W2lb, u16* __restrict__ W2rb,
                        u16* __restrict__ W3cat) {
  int i = blockIdx.x * blockDim.x + threadIdx.x;   // float4 index, total 327680
  const int S = 65536;   // 512*512/4
  const int S3 = 32768;  // 256*512/4
  const float* src; u16* dst; int o;
  if      (i <  S)          { src = w1l; dst = W1lb;            o = i; }
  else if (i <  2 * S)      { src = w1r; dst = W1rb;            o = i - S; }
  else if (i <  3 * S)      { src = w2l; dst = W2lb;            o = i - 2 * S; }
  else if (i <  4 * S)      { src = w2r; dst = W2rb;            o = i - 3 * S; }
  else if (i <  4 * S + S3) { src = w3r; dst = W3cat;           o = i - 4 * S; }
  else if (i <  4 * S + 2 * S3) { src = w3l; dst = W3cat + 256 * 512; o = i - 4 * S - S3; }
  else return;
  float4 v = ((const float4*)src)[o];
  unsigned lo = (unsigned)f2b(v.x) | ((unsigned)f2b(v.y) << 16);
  unsigned hi = (unsigned)f2b(v.z) | ((unsigned)f2b(v.w) << 16);
  ((uint2*)dst)[o] = make_uint2(lo, hi);
}

// ---------------- mean aggregation, d=512 (fp8 in, fp32 accum, bf16 out) ----------------
#ifdef HW_FP8
#define ACCQ(v)                                                               \
  do {                                                                        \
    acc2[0] += __builtin_amdgcn_cvt_pk_f32_fp8((int)(v).x, false);            \
    acc2[1] += __builtin_amdgcn_cvt_pk_f32_fp8((int)(v).x, true);             \
    acc2[2] += __builtin_amdgcn_cvt_pk_f32_fp8((int)(v).y, false);            \
    acc2[3] += __builtin_amdgcn_cvt_pk_f32_fp8((int)(v).y, true);             \
  } while (0)
#else
#define ACCQ(v)                                                               \
  do {                                                                        \
    acc2[0][0] += q2f_sw((v).x & 0xffu);         acc2[0][1] += q2f_sw(((v).x >> 8) & 0xffu);  \
    acc2[1][0] += q2f_sw(((v).x >> 16) & 0xffu); acc2[1][1] += q2f_sw((v).x >> 24);           \
    acc2[2][0] += q2f_sw((v).y & 0xffu);         acc2[2][1] += q2f_sw(((v).y >> 8) & 0xffu);  \
    acc2[3][0] += q2f_sw(((v).y >> 16) & 0xffu); acc2[3][1] += q2f_sw((v).y >> 24);           \
  } while (0)
#endif

__global__ __launch_bounds__(64) void k_agg8(
    const u8* __restrict__ xq, const int* __restrict__ row_ptr,
    const int* __restrict__ col, const float* __restrict__ inv_deg,
    u16* __restrict__ agg) {
  int node = blockIdx.x;
  int lane = threadIdx.x;
  int beg = row_ptr[node], end = row_ptr[node + 1];
  f32x2 acc2[4];
  #pragma unroll
  for (int i = 0; i < 4; ++i) acc2[i] = (f32x2){0.f, 0.f};
  int e = beg;
  for (; e + 4 <= end; e += 4) {
    int s0 = col[e], s1 = col[e + 1], s2 = col[e + 2], s3 = col[e + 3];
    uint2 v0 = *(const uint2*)&xq[(size_t)s0 * 512 + lane * 8];
    uint2 v1 = *(const uint2*)&xq[(size_t)s1 * 512 + lane * 8];
    uint2 v2 = *(const uint2*)&xq[(size_t)s2 * 512 + lane * 8];
    uint2 v3 = *(const uint2*)&xq[(size_t)s3 * 512 + lane * 8];
    ACCQ(v0); ACCQ(v1); ACCQ(v2); ACCQ(v3);
  }
  for (; e < end; ++e) {
    int s = col[e];
    uint2 v = *(const uint2*)&xq[(size_t)s * 512 + lane * 8];
    ACCQ(v);
  }
  float inv = inv_deg[node];
  uint4 ov;
  ov.x = (unsigned)f2b(acc2[0][0] * inv) | ((unsigned)f2b(acc2[0][1] * inv) << 16);
  ov.y = (unsigned)f2b(acc2[1][0] * inv) | ((unsigned)f2b(acc2[1][1] * inv) << 16);
  ov.z = (unsigned)f2b(acc2[2][0] * inv) | ((unsigned)f2b(acc2[2][1] * inv) << 16);
  ov.w = (unsigned)f2b(acc2[3][0] * inv) | ((unsigned)f2b(acc2[3][1] * inv) << 16);
  *(uint4*)&agg[(size_t)node * 512 + lane * 8] = ov;
}

// ---------------- layer-3 finish: out = r + mean_j t[j]  (write-only out) ----------------
#define ACC4(v)                                                     \
  do {                                                              \
    acc[0] += b2f((v).x & 0xffffu); acc[1] += b2f((v).x >> 16);     \
    acc[2] += b2f((v).y & 0xffffu); acc[3] += b2f((v).y >> 16);     \
  } while (0)

__global__ __launch_bounds__(64) void k_agg_add(
    const u16* __restrict__ t, const u16* __restrict__ r,
    const int* __restrict__ row_ptr,
    const int* __restrict__ col, const float* __restrict__ inv_deg,
    float* __restrict__ out) {
  int node = blockIdx.x;
  int lane = threadIdx.x;
  int beg = row_ptr[node], end = row_ptr[node + 1];
  float acc[4] = {0.f, 0.f, 0.f, 0.f};
  int e = beg;
  for (; e + 4 <= end; e += 4) {
    int s0 = col[e], s1 = col[e + 1], s2 = col[e + 2], s3 = col[e + 3];
    uint2 v0 = *(const uint2*)&t[(size_t)s0 * 256 + lane * 4];
    uint2 v1 = *(const uint2*)&t[(size_t)s1 * 256 + lane * 4];
    uint2 v2 = *(const uint2*)&t[(size_t)s2 * 256 + lane * 4];
    uint2 v3 = *(const uint2*)&t[(size_t)s3 * 256 + lane * 4];
    ACC4(v0); ACC4(v1); ACC4(v2); ACC4(v3);
  }
  for (; e < end; ++e) {
    int s = col[e];
    uint2 v = *(const uint2*)&t[(size_t)s * 256 + lane * 4];
    ACC4(v);
  }
  float inv = inv_deg[node];
  uint2 rv = *(const uint2*)&r[(size_t)node * 256 + lane * 4];
  float4 o;
  o.x = b2f(rv.x & 0xffffu) + acc[0] * inv;
  o.y = b2f(rv.x >> 16)     + acc[1] * inv;
  o.z = b2f(rv.y & 0xffffu) + acc[2] * inv;
  o.w = b2f(rv.y >> 16)     + acc[3] * inv;
  *(float4*)&out[(size_t)node * 256 + lane * 4] = o;
}

// ---------------- bf16 MFMA GEMM, XCD swizzle + LDS-coalesced bf16 epilogue ----------------
// C = sum_p A_p@W_p^T (+ bias) (, relu).  W row-major [O][K], K=512.
// mode 0: bf16 Cout (+ optional fp8 Cq), all rows  [LDS-coalesced stores]
// mode 2: cols<256 -> bf16 (Cout, pitch 256, +bias); cols>=256 -> bf16 tout (pitch 256)
#define BM 128
#define BN 128
#define BK 64
#define CT_LD 136   // C-tile LDS row pitch in u16

__global__ __launch_bounds__(256, 3) void k_gemm_mfma(
    const u16* __restrict__ A1, const u16* __restrict__ W1,
    const u16* __restrict__ A2, const u16* __restrict__ W2,
    const float* __restrict__ bias, void* __restrict__ Cout,
    u8* __restrict__ Cq, u16* __restrict__ tout,
    int O, int relu, int mode, int npass, int NX) {
  __shared__ __align__(16) u16 smem[17408];   // sA[0:8192) sB[8192:16384); ctile 128xCT_LD
  const int K = 512;
  int tid = threadIdx.x;
  int wave = tid >> 6, lane = tid & 63;

  // bijective XCD swizzle (m204)
  int nwg = gridDim.x;
  int q = nwg >> 3, r = nwg & 7;
  int xcd = blockIdx.x & 7, lin = blockIdx.x >> 3;
  int wgid = (xcd < r) ? (xcd * (q + 1) + lin)
                       : (r * (q + 1) + (xcd - r) * q + lin);
  int bx = wgid % NX, by = wgid / NX;
  int row0 = by * BM;
  int col0 = bx * BN;

  f32x4 acc[4][4];
  #pragma unroll
  for (int m = 0; m < 4; ++m)
    #pragma unroll
    for (int n = 0; n < 4; ++n)
      acc[m][n] = (f32x4){0.f, 0.f, 0.f, 0.f};

  int lrow = lane >> 3;
  int lk   = (lane & 7) * 8;
  int wr = (wave >> 1) * 64, wc = (wave & 1) * 64;
  int fr = lane & 15, fg = lane >> 4;

  for (int pass = 0; pass < npass; ++pass) {
    const u16* __restrict__ A = pass ? A2 : A1;
    const u16* __restrict__ W = pass ? W2 : W1;
    for (int k0 = 0; k0 < K; k0 += BK) {
      __syncthreads();
      #pragma unroll
      for (int i = 0; i < 4; ++i) {
        int chunk = i * 4 + wave;
        const u16* g = A + (size_t)(row0 + chunk * 8 + lrow) * K + k0 + lk;
        __builtin_amdgcn_global_load_lds(
            (const __attribute__((address_space(1))) void*)g,
            (__attribute__((address_space(3))) void*)&smem[chunk * 512],
            16, 0, 0);
      }
      #pragma unroll
      for (int i = 0; i < 4; ++i) {
        int chunk = i * 4 + wave;
        const u16* g = W + (size_t)(col0 + chunk * 8 + lrow) * K + k0 + lk;
        __builtin_amdgcn_global_load_lds(
            (const __attribute__((address_space(1))) void*)g,
            (__attribute__((address_space(3))) void*)&smem[8192 + chunk * 512],
            16, 0, 0);
      }
      __syncthreads();

      #pragma unroll
      for (int ks = 0; ks < 2; ++ks) {
        short8 a[4], b[4];
        #pragma unroll
        for (int m = 0; m < 4; ++m)
          a[m] = *(const short8*)&smem[(wr + m * 16 + fr) * BK + ks * 32 + fg * 8];
        #pragma unroll
        for (int n = 0; n < 4; ++n)
          b[n] = *(const short8*)&smem[8192 + (wc + n * 16 + fr) * BK + ks * 32 + fg * 8];
        #pragma unroll
        for (int m = 0; m < 4; ++m)
          #pragma unroll
          for (int n = 0; n < 4; ++n)
            acc[m][n] = __builtin_amdgcn_mfma_f32_16x16x32_bf16(
                a[m], b[n], acc[m][n], 0, 0, 0);
      }
    }
  }

  // all-bf16 LDS-coalesced epilogue (modes 0 and 2)
  __syncthreads();
  #pragma unroll
  for (int n = 0; n < 4; ++n) {
    int lc = wc + n * 16 + fr;
    float bv = 0.f;
    if (mode == 0) bv = bias[col0 + lc];
    else if (col0 < 256) bv = bias[col0 + lc];   // mode 2, r-half carries b3
    #pragma unroll
    for (int m = 0; m < 4; ++m) {
      #pragma unroll
      for (int j = 0; j < 4; ++j) {
        float v = acc[m][n][j] + bv;
        if (relu) v = fmaxf(v, 0.f);
        smem[(wr + m * 16 + fg * 4 + j) * CT_LD + lc] = f2b(v);
      }
    }
  }
  __syncthreads();
  #pragma unroll
  for (int it = 0; it < 8; ++it) {
    int idx = it * 256 + tid;       // 0..2047 covers 128 rows x 16 col-chunks
    int rr = idx >> 4, cc = (idx & 15) * 8;
    uint4 v = *(uint4*)&smem[rr * CT_LD + cc];
    int gr = row0 + rr;
    if (mode == 0) {
      int gc = col0 + cc;
      *(uint4*)&((u16*)Cout)[(size_t)gr * O + gc] = v;
      if (Cq) {
        unsigned w0 = pack_q4(b2f(v.x & 0xffffu), b2f(v.x >> 16),
                              b2f(v.y & 0xffffu), b2f(v.y >> 16));
        unsigned w1 = pack_q4(b2f(v.z & 0xffffu), b2f(v.z >> 16),
                              b2f(v.w & 0xffffu), b2f(v.w >> 16));
        *(uint2*)&Cq[(size_t)gr * O + gc] = make_uint2(w0, w1);
      }
    } else {   // mode 2
      if (col0 < 256) {
        *(uint4*)&((u16*)Cout)[(size_t)gr * 256 + col0 + cc] = v;      // r (bf16)
      } else {
        *(uint4*)&tout[(size_t)gr * 256 + (col0 - 256) + cc] = v;      // t (bf16)
      }
    }
  }
}

extern "C" void kernel_launch(void* const* d_in, const int* in_sizes, int n_in,
                              void* d_out, int out_size, void* d_ws, size_t ws_size,
                              hipStream_t stream) {
  const float* x    = (const float*)d_in[0];
  const int*   edge = (const int*)d_in[1];
  const int*   srcp = edge;
  const int*   dstp = edge + N_EDGES;
  const float* W1_l = (const float*)d_in[2];
  const float* b1   = (const float*)d_in[3];
  const float* W1_r = (const float*)d_in[4];
  const float* W2_l = (const float*)d_in[5];
  const float* b2   = (const float*)d_in[6];
  const float* W2_r = (const float*)d_in[7];
  const float* W3_l = (const float*)d_in[8];
  const float* b3   = (const float*)d_in[9];
  const float* W3_r = (const float*)d_in[10];
  float* out = (float*)d_out;

  char* ws = (char*)d_ws;
  size_t off = 0;
  auto alloc = [&](size_t bytes) -> void* {
    void* p = ws + off;
    off = (off + bytes + 255) & ~(size_t)255;
    return p;
  };
  u16* xb    = (u16*)alloc((size_t)M_PAD * 512 * 2);
  u16* aggb  = (u16*)alloc((size_t)M_PAD * 512 * 2);   // also reused as t (M_PAD x 256)
  u16* h1b   = (u16*)alloc((size_t)M_PAD * 512 * 2);   // also reused as r (M_PAD x 256) in layer 3
  u16* h2b   = (u16*)alloc((size_t)M_PAD * 512 * 2);
  u8*  qbuf  = (u8*)alloc((size_t)M_PAD * 512);        // xq for layer1, then h1q for layer2
  u16* W1lb  = (u16*)alloc((size_t)512 * 512 * 2);
  u16* W1rb  = (u16*)alloc((size_t)512 * 512 * 2);
  u16* W2lb  = (u16*)alloc((size_t)512 * 512 * 2);
  u16* W2rb  = (u16*)alloc((size_t)512 * 512 * 2);
  u16* W3cat = (u16*)alloc((size_t)512 * 512 * 2);     // rows 0-255 = W3_r, 256-511 = W3_l
  int*   cnt     = (int*)alloc((size_t)N_NODES * 4);
  int*   partial = (int*)alloc((size_t)N_NODES * 4);
  int*   bsum    = (int*)alloc(512 * 4);
  int*   row_ptr = (int*)alloc((size_t)(N_NODES + 1) * 4);
  int*   fillc   = (int*)alloc((size_t)N_NODES * 4);
  int*   col     = (int*)alloc((size_t)N_EDGES * 4);
  float* inv_deg = (float*)alloc((size_t)N_NODES * 4);
  (void)ws_size; (void)in_sizes; (void)n_in; (void)out_size;

  // ---- CSR build ----
  k_zero2<<<(N_NODES + 255) / 256, 256, 0, stream>>>(cnt, fillc, N_NODES);
  k_count<<<(N_EDGES + 255) / 256, 256, 0, stream>>>(dstp, cnt);
  int nb = (N_NODES + SCAN_B - 1) / SCAN_B;
  k_scan1<<<nb, SCAN_B, 0, stream>>>(cnt, partial, bsum, N_NODES);
  k_scan2<<<1, 64, 0, stream>>>(bsum, nb);
  k_scan3<<<(N_NODES + 255) / 256, 256, 0, stream>>>(partial, bsum, row_ptr, inv_deg, cnt, N_NODES);
  k_fill<<<(N_EDGES + 255) / 256, 256, 0, stream>>>(srcp, dstp, row_ptr, fillc, col);

  // ---- dtype conversions (2 launches) ----
  {
    int tx = M_PAD * 512 / 4;
    k_cvt_xq<<<(tx + 255) / 256, 256, 0, stream>>>(x, xb, qbuf);
    int tw = 4 * 65536 + 2 * 32768;   // 327680 float4s
    k_cvt_w<<<(tw + 255) / 256, 256, 0, stream>>>(W1_l, W1_r, W2_l, W2_r, W3_r, W3_l,
                                                  W1lb, W1rb, W2lb, W2rb, W3cat);
  }

  const int NWG = 4 * (M_PAD / BM);   // 1564 blocks, NX=4 (O=512)

  // ---- layer 1 ----  (agg reads xq fp8; gemm writes h1 bf16 + h1q fp8 into qbuf)
  k_agg8<<<N_NODES, 64, 0, stream>>>(qbuf, row_ptr, col, inv_deg, aggb);
  k_gemm_mfma<<<NWG, 256, 0, stream>>>(aggb, W1lb, xb, W1rb, b1, h1b, qbuf, nullptr,
                                       512, 1, 0, 2, 4);
  // ---- layer 2 ----  (agg reads h1q fp8)
  k_agg8<<<N_NODES, 64, 0, stream>>>(qbuf, row_ptr, col, inv_deg, aggb);
  k_gemm_mfma<<<NWG, 256, 0, stream>>>(aggb, W2lb, h1b, W2rb, b2, h2b, nullptr, nullptr,
                                       512, 1, 0, 2, 4);
  // ---- layer 3: single GEMM over [W3_r; W3_l]; r -> h1b (bf16,+b3), t -> aggb (bf16) ----
  k_gemm_mfma<<<NWG, 256, 0, stream>>>(h2b, W3cat, nullptr, nullptr, b3, h1b, nullptr, aggb,
                                       512, 0, 2, 1, 4);
  // out = r + mean-aggregate(t)   (write-only out)
  k_agg_add<<<N_NODES, 64, 0, stream>>>(aggb, h1b, row_ptr, col, inv_deg, out);
}

// Round 19
// 482.891 us; speedup vs baseline: 1.1239x; 1.0708x over previous
//
#include <hip/hip_runtime.h>
#include <hip/hip_bf16.h>

#define N_NODES 50000
#define N_EDGES 800000
#define M_PAD   50048   // 391 * 128
#define SCAN_B  512

typedef short short8 __attribute__((ext_vector_type(8)));
typedef float f32x4  __attribute__((ext_vector_type(4)));
typedef float f32x2  __attribute__((ext_vector_type(2)));
typedef unsigned short u16;
typedef unsigned char  u8;

#if __has_builtin(__builtin_amdgcn_cvt_pk_f32_fp8) && __has_builtin(__builtin_amdgcn_cvt_pk_fp8_f32)
#define HW_FP8 1
#endif

__device__ __forceinline__ float b2f(unsigned bits16) {
  return __uint_as_float(bits16 << 16);
}
__device__ __forceinline__ u16 f2b(float f) {   // RNE f32 -> bf16
  unsigned u = __float_as_uint(f);
  unsigned r = (u + 0x7fffu + ((u >> 16) & 1u)) >> 16;
  return (u16)r;
}
// software f32 -> fp8 e4m3 (RNE, flush |v|<2^-6 to 0; OCP-compatible bytes)
__device__ __forceinline__ unsigned f2q_sw(float f) {
  unsigned u = __float_as_uint(f);
  unsigned s = (u >> 24) & 0x80u;
  unsigned mag = u & 0x7fffffffu;
  mag += 0x7ffffu + ((mag >> 20) & 1u);
  int e = (int)(mag >> 23) - 120;
  if (e <= 0) return s;
  if (e > 15) e = 15;
  return s | ((unsigned)e << 3) | ((mag >> 20) & 7u);
}
// software fp8 e4m3 -> f32 (sw encoder never emits denormals)
__device__ __forceinline__ float q2f_sw(unsigned q) {
  unsigned s = (q & 0x80u) << 24;
  unsigned em = q & 0x7fu;
  if (em == 0) return __uint_as_float(s);
  return __uint_as_float(s | ((em + 960u) << 20));
}

// pack 4 floats -> 4 fp8 bytes
__device__ __forceinline__ unsigned pack_q4(float a, float b, float c, float d) {
#ifdef HW_FP8
  int w = __builtin_amdgcn_cvt_pk_fp8_f32(a, b, 0, false);
  w = __builtin_amdgcn_cvt_pk_fp8_f32(c, d, w, true);
  return (unsigned)w;
#else
  return f2q_sw(a) | (f2q_sw(b) << 8) | (f2q_sw(c) << 16) | (f2q_sw(d) << 24);
#endif
}
// unpack 4 fp8 bytes -> two f32x2
__device__ __forceinline__ f32x2 unpk_lo(unsigned w) {
#ifdef HW_FP8
  return __builtin_amdgcn_cvt_pk_f32_fp8((int)w, false);
#else
  return (f32x2){q2f_sw(w & 0xffu), q2f_sw((w >> 8) & 0xffu)};
#endif
}
__device__ __forceinline__ f32x2 unpk_hi(unsigned w) {
#ifdef HW_FP8
  return __builtin_amdgcn_cvt_pk_f32_fp8((int)w, true);
#else
  return (f32x2){q2f_sw((w >> 16) & 0xffu), q2f_sw(w >> 24)};
#endif
}

// ---------------- CSR build ----------------
__global__ void k_zero2(int* __restrict__ a, int* __restrict__ b, int n) {
  int i = blockIdx.x * blockDim.x + threadIdx.x;
  if (i < n) { a[i] = 0; b[i] = 0; }
}

__global__ void k_scan1(const int* __restrict__ c, int* __restrict__ partial,
                        int* __restrict__ bsum, int n) {
  __shared__ int s[SCAN_B];
  int i = blockIdx.x * SCAN_B + threadIdx.x;
  int v = (i < n) ? c[i] : 0;
  s[threadIdx.x] = v;
  __syncthreads();
  for (int off = 1; off < SCAN_B; off <<= 1) {
    int t = (threadIdx.x >= off) ? s[threadIdx.x - off] : 0;
    __syncthreads();
    s[threadIdx.x] += t;
    __syncthreads();
  }
  if (i < n) partial[i] = s[threadIdx.x];
  if (threadIdx.x == SCAN_B - 1) bsum[blockIdx.x] = s[SCAN_B - 1];
}

__global__ void k_scan2(int* __restrict__ bsum, int nb) {
  if (threadIdx.x == 0 && blockIdx.x == 0) {
    int acc = 0;
    for (int b = 0; b < nb; ++b) { int t = bsum[b]; bsum[b] = acc; acc += t; }
  }
}

__global__ void k_scan3(const int* __restrict__ partial, const int* __restrict__ bsum,
                        int* __restrict__ row_ptr, float* __restrict__ inv_deg,
                        const int* __restrict__ cnt, int n) {
  int i = blockIdx.x * blockDim.x + threadIdx.x;
  if (i == 0) row_ptr[0] = 0;
  if (i < n) {
    row_ptr[i + 1] = partial[i] + bsum[i / SCAN_B];
    int d = cnt[i];
    inv_deg[i] = 1.0f / (float)(d > 1 ? d : 1);
  }
}

__global__ void k_fill(const int* __restrict__ src, const int* __restrict__ dst,
                       const int* __restrict__ row_ptr, int* __restrict__ fillc,
                       int* __restrict__ col) {
  int e = blockIdx.x * blockDim.x + threadIdx.x;
  if (e < N_EDGES) {
    int d = dst[e];
    int pos = row_ptr[d] + atomicAdd(&fillc[d], 1);
    col[pos] = src[e];
  }
}

// ---------------- conversions ----------------
// fused: x fp32 -> bf16 (pad rows zeroed) + fp8 (single read of x); also counts edge dsts
__global__ void k_cvt_xq(const float* __restrict__ in, u16* __restrict__ outb,
                         u8* __restrict__ outq, const int* __restrict__ dst,
                         int* __restrict__ cnt) {
  int i = blockIdx.x * blockDim.x + threadIdx.x;
  if (i < N_EDGES) atomicAdd(&cnt[dst[i]], 1);
  const int total = M_PAD * 512 / 4;
  if (i >= total) return;
  float4 v = make_float4(0.f, 0.f, 0.f, 0.f);
  if (i < N_NODES * 512 / 4) v = ((const float4*)in)[i];
  unsigned lo = (unsigned)f2b(v.x) | ((unsigned)f2b(v.y) << 16);
  unsigned hi = (unsigned)f2b(v.z) | ((unsigned)f2b(v.w) << 16);
  ((uint2*)outb)[i] = make_uint2(lo, hi);
  ((unsigned*)outq)[i] = pack_q4(v.x, v.y, v.z, v.w);
}

// one kernel converting all six weight matrices (bf16), W3 concatenated [W3_r; W3_l]
__global__ void k_cvt_w(const float* __restrict__ w1l, const float* __restrict__ w1r,
                        const float* __restrict__ w2l, const float* __restrict__ w2r,
                        const float* __restrict__ w3r, const float* __restrict__ w3l,
                        u16* __restrict__ W1lb, u16* __restrict__ W1rb,
                        u16* __restrict__ W2lb, u16* __restrict__ W2rb,
                        u16* __restrict__ W3cat) {
  int i = blockIdx.x * blockDim.x + threadIdx.x;   // float4 index, total 327680
  const int S = 65536;   // 512*512/4
  const int S3 = 32768;  // 256*512/4
  const float* src; u16* dst; int o;
  if      (i <  S)          { src = w1l; dst = W1lb;            o = i; }
  else if (i <  2 * S)      { src = w1r; dst = W1rb;            o = i - S; }
  else if (i <  3 * S)      { src = w2l; dst = W2lb;            o = i - 2 * S; }
  else if (i <  4 * S)      { src = w2r; dst = W2rb;            o = i - 3 * S; }
  else if (i <  4 * S + S3) { src = w3r; dst = W3cat;           o = i - 4 * S; }
  else if (i <  4 * S + 2 * S3) { src = w3l; dst = W3cat + 256 * 512; o = i - 4 * S - S3; }
  else return;
  float4 v = ((const float4*)src)[o];
  unsigned lo = (unsigned)f2b(v.x) | ((unsigned)f2b(v.y) << 16);
  unsigned hi = (unsigned)f2b(v.z) | ((unsigned)f2b(v.w) << 16);
  ((uint2*)dst)[o] = make_uint2(lo, hi);
}

// ---------------- mean aggregation, d=512 (fp8 in, fp32 accum, bf16 out) ----------------
#define ACCQ(v)                                           \
  do {                                                    \
    acc2[0] += unpk_lo((v).x); acc2[1] += unpk_hi((v).x); \
    acc2[2] += unpk_lo((v).y); acc2[3] += unpk_hi((v).y); \
  } while (0)

__global__ __launch_bounds__(64) void k_agg8(
    const u8* __restrict__ xq, const int* __restrict__ row_ptr,
    const int* __restrict__ col, const float* __restrict__ inv_deg,
    u16* __restrict__ agg) {
  int node = blockIdx.x;
  int lane = threadIdx.x;
  int beg = row_ptr[node], end = row_ptr[node + 1];
  f32x2 acc2[4];
  #pragma unroll
  for (int i = 0; i < 4; ++i) acc2[i] = (f32x2){0.f, 0.f};
  int e = beg;
  for (; e + 4 <= end; e += 4) {
    int s0 = col[e], s1 = col[e + 1], s2 = col[e + 2], s3 = col[e + 3];
    uint2 v0 = *(const uint2*)&xq[(size_t)s0 * 512 + lane * 8];
    uint2 v1 = *(const uint2*)&xq[(size_t)s1 * 512 + lane * 8];
    uint2 v2 = *(const uint2*)&xq[(size_t)s2 * 512 + lane * 8];
    uint2 v3 = *(const uint2*)&xq[(size_t)s3 * 512 + lane * 8];
    ACCQ(v0); ACCQ(v1); ACCQ(v2); ACCQ(v3);
  }
  for (; e < end; ++e) {
    int s = col[e];
    uint2 v = *(const uint2*)&xq[(size_t)s * 512 + lane * 8];
    ACCQ(v);
  }
  float inv = inv_deg[node];
  uint4 ov;
  ov.x = (unsigned)f2b(acc2[0][0] * inv) | ((unsigned)f2b(acc2[0][1] * inv) << 16);
  ov.y = (unsigned)f2b(acc2[1][0] * inv) | ((unsigned)f2b(acc2[1][1] * inv) << 16);
  ov.z = (unsigned)f2b(acc2[2][0] * inv) | ((unsigned)f2b(acc2[2][1] * inv) << 16);
  ov.w = (unsigned)f2b(acc2[3][0] * inv) | ((unsigned)f2b(acc2[3][1] * inv) << 16);
  *(uint4*)&agg[(size_t)node * 512 + lane * 8] = ov;
}

// ---------------- layer-3 finish: out = r + mean_j tq[j]  (fp8 t gather) ----------------
__global__ __launch_bounds__(64) void k_agg_add(
    const u8* __restrict__ tq, const u16* __restrict__ r,
    const int* __restrict__ row_ptr,
    const int* __restrict__ col, const float* __restrict__ inv_deg,
    float* __restrict__ out) {
  int node = blockIdx.x;
  int lane = threadIdx.x;
  int beg = row_ptr[node], end = row_ptr[node + 1];
  f32x2 a0 = (f32x2){0.f, 0.f}, a1 = (f32x2){0.f, 0.f};
  int e = beg;
  for (; e + 4 <= end; e += 4) {
    unsigned v0 = *(const unsigned*)&tq[(size_t)col[e]     * 256 + lane * 4];
    unsigned v1 = *(const unsigned*)&tq[(size_t)col[e + 1] * 256 + lane * 4];
    unsigned v2 = *(const unsigned*)&tq[(size_t)col[e + 2] * 256 + lane * 4];
    unsigned v3 = *(const unsigned*)&tq[(size_t)col[e + 3] * 256 + lane * 4];
    a0 += unpk_lo(v0); a1 += unpk_hi(v0);
    a0 += unpk_lo(v1); a1 += unpk_hi(v1);
    a0 += unpk_lo(v2); a1 += unpk_hi(v2);
    a0 += unpk_lo(v3); a1 += unpk_hi(v3);
  }
  for (; e < end; ++e) {
    unsigned v = *(const unsigned*)&tq[(size_t)col[e] * 256 + lane * 4];
    a0 += unpk_lo(v); a1 += unpk_hi(v);
  }
  float inv = inv_deg[node];
  uint2 rv = *(const uint2*)&r[(size_t)node * 256 + lane * 4];
  float4 o;
  o.x = b2f(rv.x & 0xffffu) + a0[0] * inv;
  o.y = b2f(rv.x >> 16)     + a0[1] * inv;
  o.z = b2f(rv.y & 0xffffu) + a1[0] * inv;
  o.w = b2f(rv.y >> 16)     + a1[1] * inv;
  *(float4*)&out[(size_t)node * 256 + lane * 4] = o;
}

// ---------------- bf16 MFMA GEMM, XCD swizzle + LDS-coalesced bf16 epilogue ----------------
// C = sum_p A_p@W_p^T (+ bias) (, relu).  W row-major [O][K], K=512.
// mode 0: bf16 Cout (+ optional fp8 Cq, pitch O), all rows
// mode 2: cols<256 -> bf16 Cout (pitch 256, +bias); cols>=256 -> fp8 Cq (pitch 256)
#define BM 128
#define BN 128
#define BK 64
#define CT_LD 136   // C-tile LDS row pitch in u16

__global__ __launch_bounds__(256, 3) void k_gemm_mfma(
    const u16* __restrict__ A1, const u16* __restrict__ W1,
    const u16* __restrict__ A2, const u16* __restrict__ W2,
    const float* __restrict__ bias, void* __restrict__ Cout,
    u8* __restrict__ Cq,
    int O, int relu, int mode, int npass, int NX) {
  __shared__ __align__(16) u16 smem[17408];   // sA[0:8192) sB[8192:16384); ctile 128xCT_LD
  const int K = 512;
  int tid = threadIdx.x;
  int wave = tid >> 6, lane = tid & 63;

  // bijective XCD swizzle (m204)
  int nwg = gridDim.x;
  int q = nwg >> 3, r = nwg & 7;
  int xcd = blockIdx.x & 7, lin = blockIdx.x >> 3;
  int wgid = (xcd < r) ? (xcd * (q + 1) + lin)
                       : (r * (q + 1) + (xcd - r) * q + lin);
  int bx = wgid % NX, by = wgid / NX;
  int row0 = by * BM;
  int col0 = bx * BN;

  f32x4 acc[4][4];
  #pragma unroll
  for (int m = 0; m < 4; ++m)
    #pragma unroll
    for (int n = 0; n < 4; ++n)
      acc[m][n] = (f32x4){0.f, 0.f, 0.f, 0.f};

  int lrow = lane >> 3;
  int lk   = (lane & 7) * 8;
  int wr = (wave >> 1) * 64, wc = (wave & 1) * 64;
  int fr = lane & 15, fg = lane >> 4;

  for (int pass = 0; pass < npass; ++pass) {
    const u16* __restrict__ A = pass ? A2 : A1;
    const u16* __restrict__ W = pass ? W2 : W1;
    for (int k0 = 0; k0 < K; k0 += BK) {
      __syncthreads();
      #pragma unroll
      for (int i = 0; i < 4; ++i) {
        int chunk = i * 4 + wave;
        const u16* g = A + (size_t)(row0 + chunk * 8 + lrow) * K + k0 + lk;
        __builtin_amdgcn_global_load_lds(
            (const __attribute__((address_space(1))) void*)g,
            (__attribute__((address_space(3))) void*)&smem[chunk * 512],
            16, 0, 0);
      }
      #pragma unroll
      for (int i = 0; i < 4; ++i) {
        int chunk = i * 4 + wave;
        const u16* g = W + (size_t)(col0 + chunk * 8 + lrow) * K + k0 + lk;
        __builtin_amdgcn_global_load_lds(
            (const __attribute__((address_space(1))) void*)g,
            (__attribute__((address_space(3))) void*)&smem[8192 + chunk * 512],
            16, 0, 0);
      }
      __syncthreads();

      #pragma unroll
      for (int ks = 0; ks < 2; ++ks) {
        short8 a[4], b[4];
        #pragma unroll
        for (int m = 0; m < 4; ++m)
          a[m] = *(const short8*)&smem[(wr + m * 16 + fr) * BK + ks * 32 + fg * 8];
        #pragma unroll
        for (int n = 0; n < 4; ++n)
          b[n] = *(const short8*)&smem[8192 + (wc + n * 16 + fr) * BK + ks * 32 + fg * 8];
        #pragma unroll
        for (int m = 0; m < 4; ++m)
          #pragma unroll
          for (int n = 0; n < 4; ++n)
            acc[m][n] = __builtin_amdgcn_mfma_f32_16x16x32_bf16(
                a[m], b[n], acc[m][n], 0, 0, 0);
      }
    }
  }

  // all-bf16 LDS-coalesced epilogue (modes 0 and 2)
  __syncthreads();
  #pragma unroll
  for (int n = 0; n < 4; ++n) {
    int lc = wc + n * 16 + fr;
    float bv = 0.f;
    if (mode == 0) bv = bias[col0 + lc];
    else if (col0 < 256) bv = bias[col0 + lc];   // mode 2, r-half carries b3
    #pragma unroll
    for (int m = 0; m < 4; ++m) {
      #pragma unroll
      for (int j = 0; j < 4; ++j) {
        float v = acc[m][n][j] + bv;
        if (relu) v = fmaxf(v, 0.f);
        smem[(wr + m * 16 + fg * 4 + j) * CT_LD + lc] = f2b(v);
      }
    }
  }
  __syncthreads();
  #pragma unroll
  for (int it = 0; it < 8; ++it) {
    int idx = it * 256 + tid;       // 0..2047 covers 128 rows x 16 col-chunks
    int rr = idx >> 4, cc = (idx & 15) * 8;
    uint4 v = *(uint4*)&smem[rr * CT_LD + cc];
    int gr = row0 + rr;
    if (mode == 0) {
      int gc = col0 + cc;
      *(uint4*)&((u16*)Cout)[(size_t)gr * O + gc] = v;
      if (Cq) {
        unsigned w0 = pack_q4(b2f(v.x & 0xffffu), b2f(v.x >> 16),
                              b2f(v.y & 0xffffu), b2f(v.y >> 16));
        unsigned w1 = pack_q4(b2f(v.z & 0xffffu), b2f(v.z >> 16),
                              b2f(v.w & 0xffffu), b2f(v.w >> 16));
        *(uint2*)&Cq[(size_t)gr * O + gc] = make_uint2(w0, w1);
      }
    } else {   // mode 2
      if (col0 < 256) {
        *(uint4*)&((u16*)Cout)[(size_t)gr * 256 + col0 + cc] = v;      // r (bf16)
      } else {
        unsigned w0 = pack_q4(b2f(v.x & 0xffffu), b2f(v.x >> 16),
                              b2f(v.y & 0xffffu), b2f(v.y >> 16));
        unsigned w1 = pack_q4(b2f(v.z & 0xffffu), b2f(v.z >> 16),
                              b2f(v.w & 0xffffu), b2f(v.w >> 16));
        *(uint2*)&Cq[(size_t)gr * 256 + (col0 - 256) + cc] = make_uint2(w0, w1);  // t (fp8)
      }
    }
  }
}

extern "C" void kernel_launch(void* const* d_in, const int* in_sizes, int n_in,
                              void* d_out, int out_size, void* d_ws, size_t ws_size,
                              hipStream_t stream) {
  const float* x    = (const float*)d_in[0];
  const int*   edge = (const int*)d_in[1];
  const int*   srcp = edge;
  const int*   dstp = edge + N_EDGES;
  const float* W1_l = (const float*)d_in[2];
  const float* b1   = (const float*)d_in[3];
  const float* W1_r = (const float*)d_in[4];
  const float* W2_l = (const float*)d_in[5];
  const float* b2   = (const float*)d_in[6];
  const float* W2_r = (const float*)d_in[7];
  const float* W3_l = (const float*)d_in[8];
  const float* b3   = (const float*)d_in[9];
  const float* W3_r = (const float*)d_in[10];
  float* out = (float*)d_out;

  char* ws = (char*)d_ws;
  size_t off = 0;
  auto alloc = [&](size_t bytes) -> void* {
    void* p = ws + off;
    off = (off + bytes + 255) & ~(size_t)255;
    return p;
  };
  u16* xb    = (u16*)alloc((size_t)M_PAD * 512 * 2);
  u16* aggb  = (u16*)alloc((size_t)M_PAD * 512 * 2);
  u16* h1b   = (u16*)alloc((size_t)M_PAD * 512 * 2);   // also r (M_PAD x 256 bf16) in layer 3
  u16* h2b   = (u16*)alloc((size_t)M_PAD * 512 * 2);
  u8*  qbuf  = (u8*)alloc((size_t)M_PAD * 512);        // xq / h1q (layers 1-2), tq (layer 3)
  u16* W1lb  = (u16*)alloc((size_t)512 * 512 * 2);
  u16* W1rb  = (u16*)alloc((size_t)512 * 512 * 2);
  u16* W2lb  = (u16*)alloc((size_t)512 * 512 * 2);
  u16* W2rb  = (u16*)alloc((size_t)512 * 512 * 2);
  u16* W3cat = (u16*)alloc((size_t)512 * 512 * 2);     // rows 0-255 = W3_r, 256-511 = W3_l
  int*   cnt     = (int*)alloc((size_t)N_NODES * 4);
  int*   partial = (int*)alloc((size_t)N_NODES * 4);
  int*   bsum    = (int*)alloc(512 * 4);
  int*   row_ptr = (int*)alloc((size_t)(N_NODES + 1) * 4);
  int*   fillc   = (int*)alloc((size_t)N_NODES * 4);
  int*   col     = (int*)alloc((size_t)N_EDGES * 4);
  float* inv_deg = (float*)alloc((size_t)N_NODES * 4);
  (void)ws_size; (void)in_sizes; (void)n_in; (void)out_size;

  // ---- zero + fused cvt/count ----
  k_zero2<<<(N_NODES + 255) / 256, 256, 0, stream>>>(cnt, fillc, N_NODES);
  {
    int tx = M_PAD * 512 / 4;
    k_cvt_xq<<<(tx + 255) / 256, 256, 0, stream>>>(x, xb, qbuf, dstp, cnt);
    int tw = 4 * 65536 + 2 * 32768;   // 327680 float4s
    k_cvt_w<<<(tw + 255) / 256, 256, 0, stream>>>(W1_l, W1_r, W2_l, W2_r, W3_r, W3_l,
                                                  W1lb, W1rb, W2lb, W2rb, W3cat);
  }
  // ---- CSR scan + fill ----
  int nb = (N_NODES + SCAN_B - 1) / SCAN_B;
  k_scan1<<<nb, SCAN_B, 0, stream>>>(cnt, partial, bsum, N_NODES);
  k_scan2<<<1, 64, 0, stream>>>(bsum, nb);
  k_scan3<<<(N_NODES + 255) / 256, 256, 0, stream>>>(partial, bsum, row_ptr, inv_deg, cnt, N_NODES);
  k_fill<<<(N_EDGES + 255) / 256, 256, 0, stream>>>(srcp, dstp, row_ptr, fillc, col);

  const int NWG = 4 * (M_PAD / BM);   // 1564 blocks, NX=4 (O=512)

  // ---- layer 1 ----  (agg reads xq fp8; gemm writes h1 bf16 + h1q fp8 into qbuf)
  k_agg8<<<N_NODES, 64, 0, stream>>>(qbuf, row_ptr, col, inv_deg, aggb);
  k_gemm_mfma<<<NWG, 256, 0, stream>>>(aggb, W1lb, xb, W1rb, b1, h1b, qbuf,
                                       512, 1, 0, 2, 4);
  // ---- layer 2 ----  (agg reads h1q fp8)
  k_agg8<<<N_NODES, 64, 0, stream>>>(qbuf, row_ptr, col, inv_deg, aggb);
  k_gemm_mfma<<<NWG, 256, 0, stream>>>(aggb, W2lb, h1b, W2rb, b2, h2b, nullptr,
                                       512, 1, 0, 2, 4);
  // ---- layer 3: single GEMM over [W3_r; W3_l]; r -> h1b (bf16,+b3), t -> qbuf (fp8) ----
  k_gemm_mfma<<<NWG, 256, 0, stream>>>(h2b, W3cat, nullptr, nullptr, b3, h1b, qbuf,
                                       512, 0, 2, 1, 4);
  // out = r + mean-aggregate(tq)   (write-only out, fp8 gather)
  k_agg_add<<<N_NODES, 64, 0, stream>>>(qbuf, h1b, row_ptr, col, inv_deg, out);
}

// Round 22
// 476.963 us; speedup vs baseline: 1.1378x; 1.0124x over previous
//
#include <hip/hip_runtime.h>
#include <hip/hip_bf16.h>

#define N_NODES 50000
#define N_EDGES 800000
#define M_PAD   50048   // 391 * 128
#define SCAN_B  512

typedef short short8 __attribute__((ext_vector_type(8)));
typedef float f32x4  __attribute__((ext_vector_type(4)));
typedef float f32x2  __attribute__((ext_vector_type(2)));
typedef unsigned short u16;
typedef unsigned char  u8;

#if __has_builtin(__builtin_amdgcn_cvt_pk_f32_fp8) && __has_builtin(__builtin_amdgcn_cvt_pk_fp8_f32)
#define HW_FP8 1
#endif

__device__ __forceinline__ float b2f(unsigned bits16) {
  return __uint_as_float(bits16 << 16);
}
__device__ __forceinline__ u16 f2b(float f) {   // RNE f32 -> bf16
  unsigned u = __float_as_uint(f);
  unsigned r = (u + 0x7fffu + ((u >> 16) & 1u)) >> 16;
  return (u16)r;
}
// software f32 -> fp8 e4m3 (RNE, flush |v|<2^-6 to 0; OCP-compatible bytes)
__device__ __forceinline__ unsigned f2q_sw(float f) {
  unsigned u = __float_as_uint(f);
  unsigned s = (u >> 24) & 0x80u;
  unsigned mag = u & 0x7fffffffu;
  mag += 0x7ffffu + ((mag >> 20) & 1u);
  int e = (int)(mag >> 23) - 120;
  if (e <= 0) return s;
  if (e > 15) e = 15;
  return s | ((unsigned)e << 3) | ((mag >> 20) & 7u);
}
// software fp8 e4m3 -> f32 (sw encoder never emits denormals)
__device__ __forceinline__ float q2f_sw(unsigned q) {
  unsigned s = (q & 0x80u) << 24;
  unsigned em = q & 0x7fu;
  if (em == 0) return __uint_as_float(s);
  return __uint_as_float(s | ((em + 960u) << 20));
}

// pack 4 floats -> 4 fp8 bytes
__device__ __forceinline__ unsigned pack_q4(float a, float b, float c, float d) {
#ifdef HW_FP8
  int w = __builtin_amdgcn_cvt_pk_fp8_f32(a, b, 0, false);
  w = __builtin_amdgcn_cvt_pk_fp8_f32(c, d, w, true);
  return (unsigned)w;
#else
  return f2q_sw(a) | (f2q_sw(b) << 8) | (f2q_sw(c) << 16) | (f2q_sw(d) << 24);
#endif
}
// unpack 4 fp8 bytes -> two f32x2
__device__ __forceinline__ f32x2 unpk_lo(unsigned w) {
#ifdef HW_FP8
  return __builtin_amdgcn_cvt_pk_f32_fp8((int)w, false);
#else
  return (f32x2){q2f_sw(w & 0xffu), q2f_sw((w >> 8) & 0xffu)};
#endif
}
__device__ __forceinline__ f32x2 unpk_hi(unsigned w) {
#ifdef HW_FP8
  return __builtin_amdgcn_cvt_pk_f32_fp8((int)w, true);
#else
  return (f32x2){q2f_sw((w >> 16) & 0xffu), q2f_sw(w >> 24)};
#endif
}

// ---------------- CSR build ----------------
__global__ void k_scan1(const int* __restrict__ c, int* __restrict__ partial,
                        int* __restrict__ bsum, int n) {
  __shared__ int s[SCAN_B];
  int i = blockIdx.x * SCAN_B + threadIdx.x;
  int v = (i < n) ? c[i] : 0;
  s[threadIdx.x] = v;
  __syncthreads();
  for (int off = 1; off < SCAN_B; off <<= 1) {
    int t = (threadIdx.x >= off) ? s[threadIdx.x - off] : 0;
    __syncthreads();
    s[threadIdx.x] += t;
    __syncthreads();
  }
  if (i < n) partial[i] = s[threadIdx.x];
  if (threadIdx.x == SCAN_B - 1) bsum[blockIdx.x] = s[SCAN_B - 1];
}

// fused scan2+scan3: each 256-thread block spans exactly one SCAN_B group (g = blockIdx/2)
__global__ void k_scan3(const int* __restrict__ partial, const int* __restrict__ bsum,
                        int* __restrict__ row_ptr, float* __restrict__ inv_deg,
                        const int* __restrict__ cnt, int n) {
  __shared__ int pre;
  int g = blockIdx.x >> 1;           // 256-thread block -> group of SCAN_B=512 nodes
  if (threadIdx.x == 0) {
    int s = 0;
    for (int j = 0; j < g; ++j) s += bsum[j];
    pre = s;
  }
  __syncthreads();
  int i = blockIdx.x * blockDim.x + threadIdx.x;
  if (i == 0) row_ptr[0] = 0;
  if (i < n) {
    row_ptr[i + 1] = partial[i] + pre;
    int d = cnt[i];
    inv_deg[i] = 1.0f / (float)(d > 1 ? d : 1);
  }
}

__global__ void k_fill(const int* __restrict__ src, const int* __restrict__ dst,
                       const int* __restrict__ row_ptr, int* __restrict__ fillc,
                       int* __restrict__ col) {
  int e = blockIdx.x * blockDim.x + threadIdx.x;
  if (e < N_EDGES) {
    int d = dst[e];
    int pos = row_ptr[d] + atomicAdd(&fillc[d], 1);
    col[pos] = src[e];
  }
}

// ---------------- conversions ----------------
// fused: x fp32 -> bf16 (pad rows zeroed) + fp8 (single read of x); also counts edge dsts
__global__ void k_cvt_xq(const float* __restrict__ in, u16* __restrict__ outb,
                         u8* __restrict__ outq, const int* __restrict__ dst,
                         int* __restrict__ cnt) {
  int i = blockIdx.x * blockDim.x + threadIdx.x;
  if (i < N_EDGES) atomicAdd(&cnt[dst[i]], 1);
  const int total = M_PAD * 512 / 4;
  if (i >= total) return;
  float4 v = make_float4(0.f, 0.f, 0.f, 0.f);
  if (i < N_NODES * 512 / 4) v = ((const float4*)in)[i];
  unsigned lo = (unsigned)f2b(v.x) | ((unsigned)f2b(v.y) << 16);
  unsigned hi = (unsigned)f2b(v.z) | ((unsigned)f2b(v.w) << 16);
  ((uint2*)outb)[i] = make_uint2(lo, hi);
  ((unsigned*)outq)[i] = pack_q4(v.x, v.y, v.z, v.w);
}

// one kernel converting all six weight matrices (bf16), W3 concatenated [W3_r; W3_l]
__global__ void k_cvt_w(const float* __restrict__ w1l, const float* __restrict__ w1r,
                        const float* __restrict__ w2l, const float* __restrict__ w2r,
                        const float* __restrict__ w3r, const float* __restrict__ w3l,
                        u16* __restrict__ W1lb, u16* __restrict__ W1rb,
                        u16* __restrict__ W2lb, u16* __restrict__ W2rb,
                        u16* __restrict__ W3cat) {
  int i = blockIdx.x * blockDim.x + threadIdx.x;   // float4 index, total 327680
  const int S = 65536;   // 512*512/4
  const int S3 = 32768;  // 256*512/4
  const float* src; u16* dst; int o;
  if      (i <  S)          { src = w1l; dst = W1lb;            o = i; }
  else if (i <  2 * S)      { src = w1r; dst = W1rb;            o = i - S; }
  else if (i <  3 * S)      { src = w2l; dst = W2lb;            o = i - 2 * S; }
  else if (i <  4 * S)      { src = w2r; dst = W2rb;            o = i - 3 * S; }
  else if (i <  4 * S + S3) { src = w3r; dst = W3cat;           o = i - 4 * S; }
  else if (i <  4 * S + 2 * S3) { src = w3l; dst = W3cat + 256 * 512; o = i - 4 * S - S3; }
  else return;
  float4 v = ((const float4*)src)[o];
  unsigned lo = (unsigned)f2b(v.x) | ((unsigned)f2b(v.y) << 16);
  unsigned hi = (unsigned)f2b(v.z) | ((unsigned)f2b(v.w) << 16);
  ((uint2*)dst)[o] = make_uint2(lo, hi);
}

// ---------------- mean aggregation, d=512 (fp8 in, fp32 accum, bf16 out) ----------------
#define ACCQ(v)                                           \
  do {                                                    \
    acc2[0] += unpk_lo((v).x); acc2[1] += unpk_hi((v).x); \
    acc2[2] += unpk_lo((v).y); acc2[3] += unpk_hi((v).y); \
  } while (0)

__global__ __launch_bounds__(64) void k_agg8(
    const u8* __restrict__ xq, const int* __restrict__ row_ptr,
    const int* __restrict__ col, const float* __restrict__ inv_deg,
    u16* __restrict__ agg) {
  int node = blockIdx.x;
  int lane = threadIdx.x;
  int beg = row_ptr[node], end = row_ptr[node + 1];
  f32x2 acc2[4];
  #pragma unroll
  for (int i = 0; i < 4; ++i) acc2[i] = (f32x2){0.f, 0.f};
  int e = beg;
  for (; e + 4 <= end; e += 4) {
    int s0 = col[e], s1 = col[e + 1], s2 = col[e + 2], s3 = col[e + 3];
    uint2 v0 = *(const uint2*)&xq[(size_t)s0 * 512 + lane * 8];
    uint2 v1 = *(const uint2*)&xq[(size_t)s1 * 512 + lane * 8];
    uint2 v2 = *(const uint2*)&xq[(size_t)s2 * 512 + lane * 8];
    uint2 v3 = *(const uint2*)&xq[(size_t)s3 * 512 + lane * 8];
    ACCQ(v0); ACCQ(v1); ACCQ(v2); ACCQ(v3);
  }
  for (; e < end; ++e) {
    int s = col[e];
    uint2 v = *(const uint2*)&xq[(size_t)s * 512 + lane * 8];
    ACCQ(v);
  }
  float inv = inv_deg[node];
  uint4 ov;
  ov.x = (unsigned)f2b(acc2[0][0] * inv) | ((unsigned)f2b(acc2[0][1] * inv) << 16);
  ov.y = (unsigned)f2b(acc2[1][0] * inv) | ((unsigned)f2b(acc2[1][1] * inv) << 16);
  ov.z = (unsigned)f2b(acc2[2][0] * inv) | ((unsigned)f2b(acc2[2][1] * inv) << 16);
  ov.w = (unsigned)f2b(acc2[3][0] * inv) | ((unsigned)f2b(acc2[3][1] * inv) << 16);
  *(uint4*)&agg[(size_t)node * 512 + lane * 8] = ov;
}

// ---------------- layer-3 finish: out = r + mean_j tq[j]  (fp8 t gather) ----------------
__global__ __launch_bounds__(64) void k_agg_add(
    const u8* __restrict__ tq, const u16* __restrict__ r,
    const int* __restrict__ row_ptr,
    const int* __restrict__ col, const float* __restrict__ inv_deg,
    float* __restrict__ out) {
  int node = blockIdx.x;
  int lane = threadIdx.x;
  int beg = row_ptr[node], end = row_ptr[node + 1];
  f32x2 a0 = (f32x2){0.f, 0.f}, a1 = (f32x2){0.f, 0.f};
  int e = beg;
  for (; e + 4 <= end; e += 4) {
    unsigned v0 = *(const unsigned*)&tq[(size_t)col[e]     * 256 + lane * 4];
    unsigned v1 = *(const unsigned*)&tq[(size_t)col[e + 1] * 256 + lane * 4];
    unsigned v2 = *(const unsigned*)&tq[(size_t)col[e + 2] * 256 + lane * 4];
    unsigned v3 = *(const unsigned*)&tq[(size_t)col[e + 3] * 256 + lane * 4];
    a0 += unpk_lo(v0); a1 += unpk_hi(v0);
    a0 += unpk_lo(v1); a1 += unpk_hi(v1);
    a0 += unpk_lo(v2); a1 += unpk_hi(v2);
    a0 += unpk_lo(v3); a1 += unpk_hi(v3);
  }
  for (; e < end; ++e) {
    unsigned v = *(const unsigned*)&tq[(size_t)col[e] * 256 + lane * 4];
    a0 += unpk_lo(v); a1 += unpk_hi(v);
  }
  float inv = inv_deg[node];
  uint2 rv = *(const uint2*)&r[(size_t)node * 256 + lane * 4];
  float4 o;
  o.x = b2f(rv.x & 0xffffu) + a0[0] * inv;
  o.y = b2f(rv.x >> 16)     + a0[1] * inv;
  o.z = b2f(rv.y & 0xffffu) + a1[0] * inv;
  o.w = b2f(rv.y >> 16)     + a1[1] * inv;
  *(float4*)&out[(size_t)node * 256 + lane * 4] = o;
}

// ---------------- bf16 MFMA GEMM, XCD swizzle + LDS-coalesced bf16 epilogue ----------------
// C = sum_p A_p@W_p^T (+ bias) (, relu).  W row-major [O][K], K=512.
// mode 0: bf16 Cout (+ optional fp8 Cq, pitch O), all rows
// mode 2: cols<256 -> bf16 Cout (pitch 256, +bias); cols>=256 -> fp8 Cq (pitch 256)
#define BM 128
#define BN 128
#define BK 64
#define CT_LD 136   // C-tile LDS row pitch in u16

__global__ __launch_bounds__(256, 3) void k_gemm_mfma(
    const u16* __restrict__ A1, const u16* __restrict__ W1,
    const u16* __restrict__ A2, const u16* __restrict__ W2,
    const float* __restrict__ bias, void* __restrict__ Cout,
    u8* __restrict__ Cq,
    int O, int relu, int mode, int npass, int NX) {
  __shared__ __align__(16) u16 smem[17408];   // sA[0:8192) sB[8192:16384); ctile 128xCT_LD
  const int K = 512;
  int tid = threadIdx.x;
  int wave = tid >> 6, lane = tid & 63;

  // bijective XCD swizzle (m204)
  int nwg = gridDim.x;
  int q = nwg >> 3, r = nwg & 7;
  int xcd = blockIdx.x & 7, lin = blockIdx.x >> 3;
  int wgid = (xcd < r) ? (xcd * (q + 1) + lin)
                       : (r * (q + 1) + (xcd - r) * q + lin);
  int bx = wgid % NX, by = wgid / NX;
  int row0 = by * BM;
  int col0 = bx * BN;

  f32x4 acc[4][4];
  #pragma unroll
  for (int m = 0; m < 4; ++m)
    #pragma unroll
    for (int n = 0; n < 4; ++n)
      acc[m][n] = (f32x4){0.f, 0.f, 0.f, 0.f};

  int lrow = lane >> 3;
  int lk   = (lane & 7) * 8;
  int wr = (wave >> 1) * 64, wc = (wave & 1) * 64;
  int fr = lane & 15, fg = lane >> 4;

  for (int pass = 0; pass < npass; ++pass) {
    const u16* __restrict__ A = pass ? A2 : A1;
    const u16* __restrict__ W = pass ? W2 : W1;
    for (int k0 = 0; k0 < K; k0 += BK) {
      __syncthreads();
      #pragma unroll
      for (int i = 0; i < 4; ++i) {
        int chunk = i * 4 + wave;
        const u16* g = A + (size_t)(row0 + chunk * 8 + lrow) * K + k0 + lk;
        __builtin_amdgcn_global_load_lds(
            (const __attribute__((address_space(1))) void*)g,
            (__attribute__((address_space(3))) void*)&smem[chunk * 512],
            16, 0, 0);
      }
      #pragma unroll
      for (int i = 0; i < 4; ++i) {
        int chunk = i * 4 + wave;
        const u16* g = W + (size_t)(col0 + chunk * 8 + lrow) * K + k0 + lk;
        __builtin_amdgcn_global_load_lds(
            (const __attribute__((address_space(1))) void*)g,
            (__attribute__((address_space(3))) void*)&smem[8192 + chunk * 512],
            16, 0, 0);
      }
      __syncthreads();

      #pragma unroll
      for (int ks = 0; ks < 2; ++ks) {
        short8 a[4], b[4];
        #pragma unroll
        for (int m = 0; m < 4; ++m)
          a[m] = *(const short8*)&smem[(wr + m * 16 + fr) * BK + ks * 32 + fg * 8];
        #pragma unroll
        for (int n = 0; n < 4; ++n)
          b[n] = *(const short8*)&smem[8192 + (wc + n * 16 + fr) * BK + ks * 32 + fg * 8];
        #pragma unroll
        for (int m = 0; m < 4; ++m)
          #pragma unroll
          for (int n = 0; n < 4; ++n)
            acc[m][n] = __builtin_amdgcn_mfma_f32_16x16x32_bf16(
                a[m], b[n], acc[m][n], 0, 0, 0);
      }
    }
  }

  // all-bf16 LDS-coalesced epilogue (modes 0 and 2)
  __syncthreads();
  #pragma unroll
  for (int n = 0; n < 4; ++n) {
    int lc = wc + n * 16 + fr;
    float bv = 0.f;
    if (mode == 0) bv = bias[col0 + lc];
    else if (col0 < 256) bv = bias[col0 + lc];   // mode 2, r-half carries b3
    #pragma unroll
    for (int m = 0; m < 4; ++m) {
      #pragma unroll
      for (int j = 0; j < 4; ++j) {
        float v = acc[m][n][j] + bv;
        if (relu) v = fmaxf(v, 0.f);
        smem[(wr + m * 16 + fg * 4 + j) * CT_LD + lc] = f2b(v);
      }
    }
  }
  __syncthreads();
  #pragma unroll
  for (int it = 0; it < 8; ++it) {
    int idx = it * 256 + tid;       // 0..2047 covers 128 rows x 16 col-chunks
    int rr = idx >> 4, cc = (idx & 15) * 8;
    uint4 v = *(uint4*)&smem[rr * CT_LD + cc];
    int gr = row0 + rr;
    if (mode == 0) {
      int gc = col0 + cc;
      *(uint4*)&((u16*)Cout)[(size_t)gr * O + gc] = v;
      if (Cq) {
        unsigned w0 = pack_q4(b2f(v.x & 0xffffu), b2f(v.x >> 16),
                              b2f(v.y & 0xffffu), b2f(v.y >> 16));
        unsigned w1 = pack_q4(b2f(v.z & 0xffffu), b2f(v.z >> 16),
                              b2f(v.w & 0xffffu), b2f(v.w >> 16));
        *(uint2*)&Cq[(size_t)gr * O + gc] = make_uint2(w0, w1);
      }
    } else {   // mode 2
      if (col0 < 256) {
        *(uint4*)&((u16*)Cout)[(size_t)gr * 256 + col0 + cc] = v;      // r (bf16)
      } else {
        unsigned w0 = pack_q4(b2f(v.x & 0xffffu), b2f(v.x >> 16),
                              b2f(v.y & 0xffffu), b2f(v.y >> 16));
        unsigned w1 = pack_q4(b2f(v.z & 0xffffu), b2f(v.z >> 16),
                              b2f(v.w & 0xffffu), b2f(v.w >> 16));
        *(uint2*)&Cq[(size_t)gr * 256 + (col0 - 256) + cc] = make_uint2(w0, w1);  // t (fp8)
      }
    }
  }
}

extern "C" void kernel_launch(void* const* d_in, const int* in_sizes, int n_in,
                              void* d_out, int out_size, void* d_ws, size_t ws_size,
                              hipStream_t stream) {
  const float* x    = (const float*)d_in[0];
  const int*   edge = (const int*)d_in[1];
  const int*   srcp = edge;
  const int*   dstp = edge + N_EDGES;
  const float* W1_l = (const float*)d_in[2];
  const float* b1   = (const float*)d_in[3];
  const float* W1_r = (const float*)d_in[4];
  const float* W2_l = (const float*)d_in[5];
  const float* b2   = (const float*)d_in[6];
  const float* W2_r = (const float*)d_in[7];
  const float* W3_l = (const float*)d_in[8];
  const float* b3   = (const float*)d_in[9];
  const float* W3_r = (const float*)d_in[10];
  float* out = (float*)d_out;

  char* ws = (char*)d_ws;
  size_t off = 0;
  auto alloc = [&](size_t bytes) -> void* {
    void* p = ws + off;
    off = (off + bytes + 255) & ~(size_t)255;
    return p;
  };
  u16* xb    = (u16*)alloc((size_t)M_PAD * 512 * 2);
  u16* aggb  = (u16*)alloc((size_t)M_PAD * 512 * 2);
  u16* h1b   = (u16*)alloc((size_t)M_PAD * 512 * 2);   // also r (M_PAD x 256 bf16) in layer 3
  u16* h2b   = (u16*)alloc((size_t)M_PAD * 512 * 2);
  u8*  qbuf  = (u8*)alloc((size_t)M_PAD * 512);        // xq / h1q (layers 1-2), tq (layer 3)
  u16* W1lb  = (u16*)alloc((size_t)512 * 512 * 2);
  u16* W1rb  = (u16*)alloc((size_t)512 * 512 * 2);
  u16* W2lb  = (u16*)alloc((size_t)512 * 512 * 2);
  u16* W2rb  = (u16*)alloc((size_t)512 * 512 * 2);
  u16* W3cat = (u16*)alloc((size_t)512 * 512 * 2);     // rows 0-255 = W3_r, 256-511 = W3_l
  int*   cnt     = (int*)alloc((size_t)N_NODES * 4);   // cnt and fillc adjacent: one memset
  int*   fillc   = (int*)alloc((size_t)N_NODES * 4);
  int*   partial = (int*)alloc((size_t)N_NODES * 4);
  int*   bsum    = (int*)alloc(512 * 4);
  int*   row_ptr = (int*)alloc((size_t)(N_NODES + 1) * 4);
  int*   col     = (int*)alloc((size_t)N_EDGES * 4);
  float* inv_deg = (float*)alloc((size_t)N_NODES * 4);
  (void)ws_size; (void)in_sizes; (void)n_in; (void)out_size;

  // ---- zero (single memset over adjacent cnt+fillc, incl. alignment pad) ----
  hipMemsetAsync(cnt, 0, (char*)fillc - (char*)cnt + (size_t)N_NODES * 4, stream);
  // ---- fused cvt/count + weight cvt ----
  {
    int tx = M_PAD * 512 / 4;
    k_cvt_xq<<<(tx + 255) / 256, 256, 0, stream>>>(x, xb, qbuf, dstp, cnt);
    int tw = 4 * 65536 + 2 * 32768;   // 327680 float4s
    k_cvt_w<<<(tw + 255) / 256, 256, 0, stream>>>(W1_l, W1_r, W2_l, W2_r, W3_r, W3_l,
                                                  W1lb, W1rb, W2lb, W2rb, W3cat);
  }
  // ---- CSR scan (scan2 fused into scan3) + fill ----
  int nb = (N_NODES + SCAN_B - 1) / SCAN_B;
  k_scan1<<<nb, SCAN_B, 0, stream>>>(cnt, partial, bsum, N_NODES);
  k_scan3<<<(N_NODES + 255) / 256, 256, 0, stream>>>(partial, bsum, row_ptr, inv_deg, cnt, N_NODES);
  k_fill<<<(N_EDGES + 255) / 256, 256, 0, stream>>>(srcp, dstp, row_ptr, fillc, col);

  const int NWG = 4 * (M_PAD / BM);   // 1564 blocks, NX=4 (O=512)

  // ---- layer 1 ----  (agg reads xq fp8; gemm writes h1 bf16 + h1q fp8 into qbuf)
  k_agg8<<<N_NODES, 64, 0, stream>>>(qbuf, row_ptr, col, inv_deg, aggb);
  k_gemm_mfma<<<NWG, 256, 0, stream>>>(aggb, W1lb, xb, W1rb, b1, h1b, qbuf,
                                       512, 1, 0, 2, 4);
  // ---- layer 2 ----  (agg reads h1q fp8)
  k_agg8<<<N_NODES, 64, 0, stream>>>(qbuf, row_ptr, col, inv_deg, aggb);
  k_gemm_mfma<<<NWG, 256, 0, stream>>>(aggb, W2lb, h1b, W2rb, b2, h2b, nullptr,
                                       512, 1, 0, 2, 4);
  // ---- layer 3: single GEMM over [W3_r; W3_l]; r -> h1b (bf16,+b3), t -> qbuf (fp8) ----
  k_gemm_mfma<<<NWG, 256, 0, stream>>>(h2b, W3cat, nullptr, nullptr, b3, h1b, qbuf,
                                       512, 0, 2, 1, 4);
  // out = r + mean-aggregate(tq)   (write-only out, fp8 gather)
  k_agg_add<<<N_NODES, 64, 0, stream>>>(qbuf, h1b, row_ptr, col, inv_deg, out);
}